// Round 7
// baseline (957.098 us; speedup 1.0000x reference)
//
#include <hip/hip_runtime.h>

#define B_ROWS 262144
#define TPB 256
#define NBLK 1024         // B_ROWS / TPB, 1 row per thread; == 256 CU * 4 blocks/CU
#define NSLOT 64          // accumulation slots per stat (bid & 63)

typedef _Float16 f16;
typedef __attribute__((ext_vector_type(2))) __fp16 fp16x2_t;  // cvt_pkrtz return type
typedef __attribute__((ext_vector_type(8))) _Float16 f16x8;
typedef __attribute__((ext_vector_type(4))) float f32x4;
typedef __attribute__((ext_vector_type(16))) float f32x16;

__device__ __forceinline__ float fast_tanh(float x) {
    float e = __expf(2.0f * x);
    return 1.0f - 2.0f * __builtin_amdgcn_rcpf(e + 1.0f);
}
__device__ __forceinline__ float pkh(float a, float b) {
    fp16x2_t h = __builtin_amdgcn_cvt_pkrtz(a, b);
    return __builtin_bit_cast(float, h);
}
__device__ __forceinline__ f16x8 mk8(float a, float b, float c, float d) {
    f32x4 v = {a, b, c, d};
    return __builtin_bit_cast(f16x8, v);
}
__device__ __forceinline__ float sx32(float v) { return __shfl_xor(v, 32, 64); }

// grid barrier: monotonic generation. bar[0]=cnt, bar[1]=gen (zeroed per launch).
__device__ __forceinline__ void gbar(unsigned* bar, unsigned target) {
    __syncthreads();
    if (threadIdx.x == 0) {
        __threadfence();
        unsigned old = __hip_atomic_fetch_add(&bar[0], 1u, __ATOMIC_ACQ_REL,
                                              __HIP_MEMORY_SCOPE_AGENT);
        if (old == target * NBLK - 1) {
            __hip_atomic_store(&bar[1], target, __ATOMIC_RELEASE,
                               __HIP_MEMORY_SCOPE_AGENT);
        } else {
            while (__hip_atomic_load(&bar[1], __ATOMIC_ACQUIRE,
                                     __HIP_MEMORY_SCOPE_AGENT) < target)
                __builtin_amdgcn_s_sleep(1);
        }
        __threadfence();
    }
    __syncthreads();
}

// ---------------------------------------------------------------------------
// Setup: pack W2 / Wf into MFMA A-fragment order (A = W^T), f16.
// ---------------------------------------------------------------------------
__global__ void __launch_bounds__(TPB)
pack_weights(const float* __restrict__ W2, const float* __restrict__ Wf,
             f16* __restrict__ w2pk, f16* __restrict__ wfpk)
{
    int i = blockIdx.x * TPB + threadIdx.x;     // 0 .. 16383
    int which = i >> 13;
    int t  = i & 8191;
    int j  = t & 7;
    int ln = (t >> 3) & 63;
    int kh = (t >> 9) & 1;
    int L  = t >> 10;
    int k  = kh * 16 + ((ln >> 5) << 3) + j;
    if (which == 0) {
        w2pk[t] = (f16)W2[L * 1024 + k * 32 + (ln & 31)];
    } else {
        int row = ln & 31;
        wfpk[t] = (row < 8) ? (f16)Wf[L * 256 + k * 8 + row] : (f16)0.f;
    }
}

// ---------------------------------------------------------------------------
// Fused persistent kernel: all 8 layers; z, logdet in registers throughout.
// Cross-block stats flow ONLY through device-scope atomics (slots[9][16][64]).
// ---------------------------------------------------------------------------
__global__ void __launch_bounds__(TPB, 4)
flow_fused(const float* __restrict__ x,    const float* __restrict__ logdet,
           const float* __restrict__ bvec, const float* __restrict__ logs,
           const float* __restrict__ log_gamma,
           const float* __restrict__ W1,   const float* __restrict__ b1,
           const float* __restrict__ b2,   const float* __restrict__ bf,
           const f16* __restrict__ w2pk,   const f16* __restrict__ wfpk,
           float* __restrict__ out,        float* slots,
           unsigned* __restrict__ bar)
{
    const int tid  = threadIdx.x;
    const int bid  = blockIdx.x;
    const int lane = tid & 63;
    const int wid  = tid >> 6;
    const bool lo  = lane < 32;
    const int slot = bid & (NSLOT - 1);
    const size_t r0 = (size_t)bid * TPB + tid;

    __shared__ float lred[64];

    // ---- load row + logdet (persistent registers) ----
    float z[8];
    {
        const float4* p0 = reinterpret_cast<const float4*>(x + r0 * 8);
        float4 a = p0[0], c = p0[1];
        z[0]=a.x; z[1]=a.y; z[2]=a.z; z[3]=a.w;
        z[4]=c.x; z[5]=c.y; z[6]=c.z; z[7]=c.w;
    }
    float ldv = logdet[r0];

    // ---- initial partials of x -> slots[0] ----
    {
        float acc[16];
        #pragma unroll
        for (int j = 0; j < 8; ++j) { acc[j] = z[j]; acc[8 + j] = z[j] * z[j]; }
        #pragma unroll
        for (int d = 1; d < 64; d <<= 1) {
            #pragma unroll
            for (int j = 0; j < 16; ++j) acc[j] += __shfl_xor(acc[j], d, 64);
        }
        if (lane == 0) {
            #pragma unroll
            for (int j = 0; j < 16; ++j) lred[wid * 16 + j] = acc[j];
        }
        __syncthreads();
        if (tid < 16) {
            float s = lred[tid] + lred[16 + tid] + lred[32 + tid] + lred[48 + tid];
            __hip_atomic_fetch_add(&slots[tid * NSLOT + slot], s,
                                   __ATOMIC_RELAXED, __HIP_MEMORY_SCOPE_AGENT);
        }
    }
    gbar(bar, 1);

    #pragma unroll 1
    for (int L = 0; L < 8; ++L) {
        // ---- stats: wave 0 atomically reads the 16x64 slots, butterfly, LDS bcast
        float tot[16];
        {
            float* sl = slots + (size_t)L * (16 * NSLOT);
            if (wid == 0) {
                float a16[16];
                #pragma unroll
                for (int j = 0; j < 16; ++j)
                    a16[j] = __hip_atomic_load(&sl[j * NSLOT + lane],
                                               __ATOMIC_RELAXED,
                                               __HIP_MEMORY_SCOPE_AGENT);
                #pragma unroll
                for (int d = 1; d < 64; d <<= 1) {
                    #pragma unroll
                    for (int j = 0; j < 16; ++j) a16[j] += __shfl_xor(a16[j], d, 64);
                }
                if (lane == 0) {
                    #pragma unroll
                    for (int j = 0; j < 16; ++j) lred[j] = a16[j];
                }
            }
            __syncthreads();
            #pragma unroll
            for (int j = 0; j < 16; ++j) tot[j] = lred[j];
            __syncthreads();   // all reads done before lred reuse
        }

        const float invB = 1.0f / (float)B_ROWS;
        float es[8], beta[8];
        float sum_s = 0.f;
        #pragma unroll
        for (int j = 0; j < 8; ++j) {
            float m = tot[j] * invB;
            float q = tot[8 + j] * invB;
            float v = q - m * m;
            v = v < 0.f ? 0.f : v;
            float li = -(1.0f / 3.0f) * __logf(sqrtf(v) + 1e-6f);
            float s = logs[L * 8 + j] + li;
            s = s < -5.f ? -5.f : (s > 5.f ? 5.f : s);
            es[j]   = __expf(s);
            beta[j] = bvec[L * 8 + j] - m;
            sum_s  += s;
        }
        float gfac[4];
        #pragma unroll
        for (int j = 0; j < 4; ++j) {
            float lg = log_gamma[L * 4 + j];
            lg = lg < -5.f ? -5.f : (lg > 5.f ? 5.f : lg);
            gfac[j] = __expf(lg);
        }

        // ---- actnorm ----
        #pragma unroll
        for (int j = 0; j < 8; ++j)
            z[j] = (z[j] + beta[j]) * es[j];

        // ---- W1: 4 -> 32, fp32 VALU ----
        const float* w1  = W1 + L * (4 * 32);
        const float* vb1 = b1 + L * 32;
        const float* vb2 = b2 + L * 32;
        const float* vbf = bf + L * 8;

        float h1[32];
        #pragma unroll
        for (int w = 0; w < 32; ++w) {
            float t = vb1[w];
            #pragma unroll
            for (int k = 0; k < 4; ++k)
                t += z[k] * w1[k * 32 + w];
            h1[w] = t > 0.f ? t : 0.f;
        }

        // ---- pack h1 -> f16 pairs; W2 B-fragments ----
        float hp[16];
        #pragma unroll
        for (int c = 0; c < 16; ++c) hp[c] = pkh(h1[2 * c], h1[2 * c + 1]);
        float Sv[16];
        #pragma unroll
        for (int c = 0; c < 16; ++c) Sv[c] = sx32(hp[c]);

        f16x8 B00 = mk8(lo?hp[0]:Sv[4],  lo?hp[1]:Sv[5],  lo?hp[2]:Sv[6],  lo?hp[3]:Sv[7]);
        f16x8 B01 = mk8(lo?hp[8]:Sv[12], lo?hp[9]:Sv[13], lo?hp[10]:Sv[14],lo?hp[11]:Sv[15]);
        f16x8 B10 = mk8(lo?Sv[0]:hp[4],  lo?Sv[1]:hp[5],  lo?Sv[2]:hp[6],  lo?Sv[3]:hp[7]);
        f16x8 B11 = mk8(lo?Sv[8]:hp[12], lo?Sv[9]:hp[13], lo?Sv[10]:hp[14],lo?Sv[11]:hp[15]);

        const f16x8* w2p = reinterpret_cast<const f16x8*>(w2pk);
        f16x8 A0 = w2p[(L * 2 + 0) * 64 + lane];
        f16x8 A1 = w2p[(L * 2 + 1) * 64 + lane];

        f32x16 d0 = {}, d1 = {};
        d0 = __builtin_amdgcn_mfma_f32_32x32x16_f16(A0, B00, d0, 0, 0, 0);
        d0 = __builtin_amdgcn_mfma_f32_32x32x16_f16(A1, B01, d0, 0, 0, 0);
        d1 = __builtin_amdgcn_mfma_f32_32x32x16_f16(A0, B10, d1, 0, 0, 0);
        d1 = __builtin_amdgcn_mfma_f32_32x32x16_f16(A1, B11, d1, 0, 0, 0);

        float h2g0[16], h2g1[16];
        #pragma unroll
        for (int r = 0; r < 16; ++r) {
            int wlo = (r & 3) + 8 * (r >> 2);
            float bsel = lo ? vb2[wlo] : vb2[wlo + 4];
            float a = d0[r] + bsel; h2g0[r] = a > 0.f ? a : 0.f;
            float b = d1[r] + bsel; h2g1[r] = b > 0.f ? b : 0.f;
        }

        float P0[8], P1[8], X0[8], X1[8];
        #pragma unroll
        for (int c = 0; c < 8; ++c) {
            P0[c] = pkh(h2g0[2 * c], h2g0[2 * c + 1]);
            P1[c] = pkh(h2g1[2 * c], h2g1[2 * c + 1]);
        }
        #pragma unroll
        for (int c = 0; c < 8; ++c) { X0[c] = sx32(P0[c]); X1[c] = sx32(P1[c]); }

        f16x8 C00 = mk8(lo?P0[0]:X0[2], lo?P0[1]:X0[3], lo?X0[0]:P0[2], lo?X0[1]:P0[3]);
        f16x8 C01 = mk8(lo?P0[4]:X0[6], lo?P0[5]:X0[7], lo?X0[4]:P0[6], lo?X0[5]:P0[7]);
        f16x8 C10 = mk8(lo?P1[0]:X1[2], lo?P1[1]:X1[3], lo?X1[0]:P1[2], lo?X1[1]:P1[3]);
        f16x8 C11 = mk8(lo?P1[4]:X1[6], lo?P1[5]:X1[7], lo?X1[4]:P1[6], lo?X1[5]:P1[7]);

        const f16x8* wfp = reinterpret_cast<const f16x8*>(wfpk);
        f16x8 F0 = wfp[(L * 2 + 0) * 64 + lane];
        f16x8 F1 = wfp[(L * 2 + 1) * 64 + lane];

        f32x16 e0 = {}, e1 = {};
        e0 = __builtin_amdgcn_mfma_f32_32x32x16_f16(F0, C00, e0, 0, 0, 0);
        e0 = __builtin_amdgcn_mfma_f32_32x32x16_f16(F1, C01, e0, 0, 0, 0);
        e1 = __builtin_amdgcn_mfma_f32_32x32x16_f16(F0, C10, e1, 0, 0, 0);
        e1 = __builtin_amdgcn_mfma_f32_32x32x16_f16(F1, C11, e1, 0, 0, 0);

        float h3[8];
        #pragma unroll
        for (int r = 0; r < 4; ++r) {
            float s0 = sx32(e0[r]);
            float s1 = sx32(e1[r]);
            h3[r]     = (lo ? e0[r] : s1) + vbf[r];
            h3[r + 4] = (lo ? s0 : e1[r]) + vbf[r + 4];
        }

        // ---- coupling epilogue + permutation + next-layer partials ----
        float nacc[16];
        {
            float ldl = 0.f;
            float nz[8];
            #pragma unroll
            for (int j = 0; j < 4; ++j) {
                float sc = 0.6f * fast_tanh(h3[2 * j + 1]);
                float sh = gfac[j] * fast_tanh(h3[2 * j]);
                float z2 = z[4 + j];
                z2 = z2 + sc * z2 + sh;
                ldl += __logf(1.0f + sc);
                nz[3 - j] = z2;      // reversed: out[3-j] = z2_j
                nz[7 - j] = z[j];    // reversed: out[7-j] = z1_j
            }
            ldv += sum_s + ldl;
            #pragma unroll
            for (int j = 0; j < 8; ++j) {
                z[j] = nz[j];
                nacc[j]     = nz[j];
                nacc[8 + j] = nz[j] * nz[j];
            }
        }

        if (L < 7) {
            #pragma unroll
            for (int d = 1; d < 64; d <<= 1) {
                #pragma unroll
                for (int j = 0; j < 16; ++j) nacc[j] += __shfl_xor(nacc[j], d, 64);
            }
            if (lane == 0) {
                #pragma unroll
                for (int j = 0; j < 16; ++j) lred[wid * 16 + j] = nacc[j];
            }
            __syncthreads();
            if (tid < 16) {
                float s = lred[tid] + lred[16 + tid] + lred[32 + tid] + lred[48 + tid];
                __hip_atomic_fetch_add(&slots[(size_t)(L + 1) * (16 * NSLOT) +
                                              tid * NSLOT + slot], s,
                                       __ATOMIC_RELAXED, __HIP_MEMORY_SCOPE_AGENT);
            }
            gbar(bar, (unsigned)(L + 2));
        }
    }

    // ---- store outputs: z (B,8) then ld (B,1) ----
    {
        float4* p0 = reinterpret_cast<float4*>(out + r0 * 8);
        float4 a, c;
        a.x=z[0]; a.y=z[1]; a.z=z[2]; a.w=z[3];
        c.x=z[4]; c.y=z[5]; c.z=z[6]; c.w=z[7];
        p0[0] = a; p0[1] = c;
    }
    out[(size_t)B_ROWS * 8 + r0] = ldv;
}

extern "C" void kernel_launch(void* const* d_in, const int* in_sizes, int n_in,
                              void* d_out, int out_size, void* d_ws, size_t ws_size,
                              hipStream_t stream) {
    const float* x      = (const float*)d_in[0];
    const float* logdet = (const float*)d_in[1];
    const float* bvec   = (const float*)d_in[2];
    const float* logs   = (const float*)d_in[3];
    const float* lg     = (const float*)d_in[4];
    const float* W1     = (const float*)d_in[5];
    const float* b1     = (const float*)d_in[6];
    const float* W2     = (const float*)d_in[7];
    const float* b2     = (const float*)d_in[8];
    const float* Wf     = (const float*)d_in[9];
    const float* bf     = (const float*)d_in[10];
    float* out = (float*)d_out;

    // ws layout (bytes): w2pk[16384] | wfpk[16384] | slots[9*16*64 f32] | bar[4 u32]
    f16*      w2pk  = (f16*)d_ws;
    f16*      wfpk  = w2pk + 8192;
    float*    slots = (float*)(wfpk + 8192);
    unsigned* bar   = (unsigned*)(slots + 9 * 16 * NSLOT);

    // zero slots + bar in one async memset (graph-capture legal)
    hipMemsetAsync(slots, 0, 9 * 16 * NSLOT * sizeof(float) + 4 * sizeof(unsigned),
                   stream);
    pack_weights<<<64, TPB, 0, stream>>>(W2, Wf, w2pk, wfpk);

    void* args[] = {&x, &logdet, &bvec, &logs, &lg, &W1, &b1, &b2, &bf,
                    &w2pk, &wfpk, &out, &slots, &bar};
    hipLaunchKernel(reinterpret_cast<void*>(&flow_fused),
                    dim3(NBLK), dim3(TPB), args, 0, stream);
}

// Round 8
// 583.555 us; speedup vs baseline: 1.6401x; 1.6401x over previous
//
#include <hip/hip_runtime.h>

#define B_ROWS 262144
#define TPB 256
#define NBLK 1024         // B_ROWS / TPB, 1 row per thread; == 256 CU * 4 blocks/CU
#define NSLOT 64          // accumulation slots per stat (bid & 63)

typedef _Float16 f16;
typedef __attribute__((ext_vector_type(2))) __fp16 fp16x2_t;  // cvt_pkrtz return type
typedef __attribute__((ext_vector_type(8))) _Float16 f16x8;
typedef __attribute__((ext_vector_type(4))) float f32x4;
typedef __attribute__((ext_vector_type(16))) float f32x16;

__device__ __forceinline__ float fast_tanh(float x) {
    float e = __expf(2.0f * x);
    return 1.0f - 2.0f * __builtin_amdgcn_rcpf(e + 1.0f);
}
__device__ __forceinline__ float pkh(float a, float b) {
    fp16x2_t h = __builtin_amdgcn_cvt_pkrtz(a, b);
    return __builtin_bit_cast(float, h);
}
__device__ __forceinline__ f16x8 mk8(float a, float b, float c, float d) {
    f32x4 v = {a, b, c, d};
    return __builtin_bit_cast(f16x8, v);
}
__device__ __forceinline__ float sx32(float v) { return __shfl_xor(v, 32, 64); }

// grid barrier: monotonic generation, NO fences, RELAXED polling.
// HB chain: slot writes -sb-> fetch_add(ACQ_REL) -RMW release seq-> last arriver
// -sb-> store(gen, RELEASE) -rf-> final ACQUIRE load below -sb-> slot reads.
__device__ __forceinline__ void gbar(unsigned* bar, unsigned target) {
    __syncthreads();
    if (threadIdx.x == 0) {
        unsigned old = __hip_atomic_fetch_add(&bar[0], 1u, __ATOMIC_ACQ_REL,
                                              __HIP_MEMORY_SCOPE_AGENT);
        if (old == target * NBLK - 1) {
            __hip_atomic_store(&bar[1], target, __ATOMIC_RELEASE,
                               __HIP_MEMORY_SCOPE_AGENT);
        } else {
            while (__hip_atomic_load(&bar[1], __ATOMIC_RELAXED,
                                     __HIP_MEMORY_SCOPE_AGENT) < target)
                __builtin_amdgcn_s_sleep(8);
            // single sync edge (read-read coherence: sees >= target)
            (void)__hip_atomic_load(&bar[1], __ATOMIC_ACQUIRE,
                                    __HIP_MEMORY_SCOPE_AGENT);
        }
    }
    __syncthreads();
}

// ---------------------------------------------------------------------------
// Setup: pack W2 / Wf into MFMA A-fragment order (A = W^T), f16.
// ---------------------------------------------------------------------------
__global__ void __launch_bounds__(TPB)
pack_weights(const float* __restrict__ W2, const float* __restrict__ Wf,
             f16* __restrict__ w2pk, f16* __restrict__ wfpk)
{
    int i = blockIdx.x * TPB + threadIdx.x;     // 0 .. 16383
    int which = i >> 13;
    int t  = i & 8191;
    int j  = t & 7;
    int ln = (t >> 3) & 63;
    int kh = (t >> 9) & 1;
    int L  = t >> 10;
    int k  = kh * 16 + ((ln >> 5) << 3) + j;
    if (which == 0) {
        w2pk[t] = (f16)W2[L * 1024 + k * 32 + (ln & 31)];
    } else {
        int row = ln & 31;
        wfpk[t] = (row < 8) ? (f16)Wf[L * 256 + k * 8 + row] : (f16)0.f;
    }
}

// ---------------------------------------------------------------------------
// Fused persistent kernel: all 8 layers; z, logdet in registers throughout.
// Cross-block stats flow ONLY through device-scope atomics (slots[9][16][64]).
// ---------------------------------------------------------------------------
__global__ void __launch_bounds__(TPB, 4)
flow_fused(const float* __restrict__ x,    const float* __restrict__ logdet,
           const float* __restrict__ bvec, const float* __restrict__ logs,
           const float* __restrict__ log_gamma,
           const float* __restrict__ W1,   const float* __restrict__ b1,
           const float* __restrict__ b2,   const float* __restrict__ bf,
           const f16* __restrict__ w2pk,   const f16* __restrict__ wfpk,
           float* __restrict__ out,        float* slots,
           unsigned* __restrict__ bar)
{
    const int tid  = threadIdx.x;
    const int bid  = blockIdx.x;
    const int lane = tid & 63;
    const int wid  = tid >> 6;
    const bool lo  = lane < 32;
    const int slot = bid & (NSLOT - 1);
    const size_t r0 = (size_t)bid * TPB + tid;

    __shared__ float lred[64];

    // ---- load row + logdet (persistent registers) ----
    float z[8];
    {
        const float4* p0 = reinterpret_cast<const float4*>(x + r0 * 8);
        float4 a = p0[0], c = p0[1];
        z[0]=a.x; z[1]=a.y; z[2]=a.z; z[3]=a.w;
        z[4]=c.x; z[5]=c.y; z[6]=c.z; z[7]=c.w;
    }
    float ldv = logdet[r0];

    // ---- initial partials of x -> slots[0] ----
    {
        float acc[16];
        #pragma unroll
        for (int j = 0; j < 8; ++j) { acc[j] = z[j]; acc[8 + j] = z[j] * z[j]; }
        #pragma unroll
        for (int d = 1; d < 64; d <<= 1) {
            #pragma unroll
            for (int j = 0; j < 16; ++j) acc[j] += __shfl_xor(acc[j], d, 64);
        }
        if (lane == 0) {
            #pragma unroll
            for (int j = 0; j < 16; ++j) lred[wid * 16 + j] = acc[j];
        }
        __syncthreads();
        if (tid < 16) {
            float s = lred[tid] + lred[16 + tid] + lred[32 + tid] + lred[48 + tid];
            __hip_atomic_fetch_add(&slots[tid * NSLOT + slot], s,
                                   __ATOMIC_RELAXED, __HIP_MEMORY_SCOPE_AGENT);
        }
    }
    gbar(bar, 1);

    #pragma unroll 1
    for (int L = 0; L < 8; ++L) {
        // ---- stats: wave 0 atomically reads the 16x64 slots, butterfly, LDS bcast
        float tot[16];
        {
            float* sl = slots + (size_t)L * (16 * NSLOT);
            if (wid == 0) {
                float a16[16];
                #pragma unroll
                for (int j = 0; j < 16; ++j)
                    a16[j] = __hip_atomic_load(&sl[j * NSLOT + lane],
                                               __ATOMIC_RELAXED,
                                               __HIP_MEMORY_SCOPE_AGENT);
                #pragma unroll
                for (int d = 1; d < 64; d <<= 1) {
                    #pragma unroll
                    for (int j = 0; j < 16; ++j) a16[j] += __shfl_xor(a16[j], d, 64);
                }
                if (lane == 0) {
                    #pragma unroll
                    for (int j = 0; j < 16; ++j) lred[j] = a16[j];
                }
            }
            __syncthreads();
            #pragma unroll
            for (int j = 0; j < 16; ++j) tot[j] = lred[j];
            __syncthreads();   // all reads done before lred reuse
        }

        const float invB = 1.0f / (float)B_ROWS;
        float es[8], beta[8];
        float sum_s = 0.f;
        #pragma unroll
        for (int j = 0; j < 8; ++j) {
            float m = tot[j] * invB;
            float q = tot[8 + j] * invB;
            float v = q - m * m;
            v = v < 0.f ? 0.f : v;
            float li = -(1.0f / 3.0f) * __logf(sqrtf(v) + 1e-6f);
            float s = logs[L * 8 + j] + li;
            s = s < -5.f ? -5.f : (s > 5.f ? 5.f : s);
            es[j]   = __expf(s);
            beta[j] = bvec[L * 8 + j] - m;
            sum_s  += s;
        }
        float gfac[4];
        #pragma unroll
        for (int j = 0; j < 4; ++j) {
            float lg = log_gamma[L * 4 + j];
            lg = lg < -5.f ? -5.f : (lg > 5.f ? 5.f : lg);
            gfac[j] = __expf(lg);
        }

        // ---- actnorm ----
        #pragma unroll
        for (int j = 0; j < 8; ++j)
            z[j] = (z[j] + beta[j]) * es[j];

        // ---- W1: 4 -> 32, fp32 VALU ----
        const float* w1  = W1 + L * (4 * 32);
        const float* vb1 = b1 + L * 32;
        const float* vb2 = b2 + L * 32;
        const float* vbf = bf + L * 8;

        float h1[32];
        #pragma unroll
        for (int w = 0; w < 32; ++w) {
            float t = vb1[w];
            #pragma unroll
            for (int k = 0; k < 4; ++k)
                t += z[k] * w1[k * 32 + w];
            h1[w] = t > 0.f ? t : 0.f;
        }

        // ---- pack h1 -> f16 pairs; W2 B-fragments ----
        float hp[16];
        #pragma unroll
        for (int c = 0; c < 16; ++c) hp[c] = pkh(h1[2 * c], h1[2 * c + 1]);
        float Sv[16];
        #pragma unroll
        for (int c = 0; c < 16; ++c) Sv[c] = sx32(hp[c]);

        f16x8 B00 = mk8(lo?hp[0]:Sv[4],  lo?hp[1]:Sv[5],  lo?hp[2]:Sv[6],  lo?hp[3]:Sv[7]);
        f16x8 B01 = mk8(lo?hp[8]:Sv[12], lo?hp[9]:Sv[13], lo?hp[10]:Sv[14],lo?hp[11]:Sv[15]);
        f16x8 B10 = mk8(lo?Sv[0]:hp[4],  lo?Sv[1]:hp[5],  lo?Sv[2]:hp[6],  lo?Sv[3]:hp[7]);
        f16x8 B11 = mk8(lo?Sv[8]:hp[12], lo?Sv[9]:hp[13], lo?Sv[10]:hp[14],lo?Sv[11]:hp[15]);

        const f16x8* w2p = reinterpret_cast<const f16x8*>(w2pk);
        f16x8 A0 = w2p[(L * 2 + 0) * 64 + lane];
        f16x8 A1 = w2p[(L * 2 + 1) * 64 + lane];

        f32x16 d0 = {}, d1 = {};
        d0 = __builtin_amdgcn_mfma_f32_32x32x16_f16(A0, B00, d0, 0, 0, 0);
        d0 = __builtin_amdgcn_mfma_f32_32x32x16_f16(A1, B01, d0, 0, 0, 0);
        d1 = __builtin_amdgcn_mfma_f32_32x32x16_f16(A0, B10, d1, 0, 0, 0);
        d1 = __builtin_amdgcn_mfma_f32_32x32x16_f16(A1, B11, d1, 0, 0, 0);

        float h2g0[16], h2g1[16];
        #pragma unroll
        for (int r = 0; r < 16; ++r) {
            int wlo = (r & 3) + 8 * (r >> 2);
            float bsel = lo ? vb2[wlo] : vb2[wlo + 4];
            float a = d0[r] + bsel; h2g0[r] = a > 0.f ? a : 0.f;
            float b = d1[r] + bsel; h2g1[r] = b > 0.f ? b : 0.f;
        }

        float P0[8], P1[8], X0[8], X1[8];
        #pragma unroll
        for (int c = 0; c < 8; ++c) {
            P0[c] = pkh(h2g0[2 * c], h2g0[2 * c + 1]);
            P1[c] = pkh(h2g1[2 * c], h2g1[2 * c + 1]);
        }
        #pragma unroll
        for (int c = 0; c < 8; ++c) { X0[c] = sx32(P0[c]); X1[c] = sx32(P1[c]); }

        f16x8 C00 = mk8(lo?P0[0]:X0[2], lo?P0[1]:X0[3], lo?X0[0]:P0[2], lo?X0[1]:P0[3]);
        f16x8 C01 = mk8(lo?P0[4]:X0[6], lo?P0[5]:X0[7], lo?X0[4]:P0[6], lo?X0[5]:P0[7]);
        f16x8 C10 = mk8(lo?P1[0]:X1[2], lo?P1[1]:X1[3], lo?X1[0]:P1[2], lo?X1[1]:P1[3]);
        f16x8 C11 = mk8(lo?P1[4]:X1[6], lo?P1[5]:X1[7], lo?X1[4]:P1[6], lo?X1[5]:P1[7]);

        const f16x8* wfp = reinterpret_cast<const f16x8*>(wfpk);
        f16x8 F0 = wfp[(L * 2 + 0) * 64 + lane];
        f16x8 F1 = wfp[(L * 2 + 1) * 64 + lane];

        f32x16 e0 = {}, e1 = {};
        e0 = __builtin_amdgcn_mfma_f32_32x32x16_f16(F0, C00, e0, 0, 0, 0);
        e0 = __builtin_amdgcn_mfma_f32_32x32x16_f16(F1, C01, e0, 0, 0, 0);
        e1 = __builtin_amdgcn_mfma_f32_32x32x16_f16(F0, C10, e1, 0, 0, 0);
        e1 = __builtin_amdgcn_mfma_f32_32x32x16_f16(F1, C11, e1, 0, 0, 0);

        float h3[8];
        #pragma unroll
        for (int r = 0; r < 4; ++r) {
            float s0 = sx32(e0[r]);
            float s1 = sx32(e1[r]);
            h3[r]     = (lo ? e0[r] : s1) + vbf[r];
            h3[r + 4] = (lo ? s0 : e1[r]) + vbf[r + 4];
        }

        // ---- coupling epilogue + permutation + next-layer partials ----
        float nacc[16];
        {
            float ldl = 0.f;
            float nz[8];
            #pragma unroll
            for (int j = 0; j < 4; ++j) {
                float sc = 0.6f * fast_tanh(h3[2 * j + 1]);
                float sh = gfac[j] * fast_tanh(h3[2 * j]);
                float z2 = z[4 + j];
                z2 = z2 + sc * z2 + sh;
                ldl += __logf(1.0f + sc);
                nz[3 - j] = z2;      // reversed: out[3-j] = z2_j
                nz[7 - j] = z[j];    // reversed: out[7-j] = z1_j
            }
            ldv += sum_s + ldl;
            #pragma unroll
            for (int j = 0; j < 8; ++j) {
                z[j] = nz[j];
                nacc[j]     = nz[j];
                nacc[8 + j] = nz[j] * nz[j];
            }
        }

        if (L < 7) {
            #pragma unroll
            for (int d = 1; d < 64; d <<= 1) {
                #pragma unroll
                for (int j = 0; j < 16; ++j) nacc[j] += __shfl_xor(nacc[j], d, 64);
            }
            if (lane == 0) {
                #pragma unroll
                for (int j = 0; j < 16; ++j) lred[wid * 16 + j] = nacc[j];
            }
            __syncthreads();
            if (tid < 16) {
                float s = lred[tid] + lred[16 + tid] + lred[32 + tid] + lred[48 + tid];
                __hip_atomic_fetch_add(&slots[(size_t)(L + 1) * (16 * NSLOT) +
                                              tid * NSLOT + slot], s,
                                       __ATOMIC_RELAXED, __HIP_MEMORY_SCOPE_AGENT);
            }
            gbar(bar, (unsigned)(L + 2));
        }
    }

    // ---- store outputs: z (B,8) then ld (B,1) ----
    {
        float4* p0 = reinterpret_cast<float4*>(out + r0 * 8);
        float4 a, c;
        a.x=z[0]; a.y=z[1]; a.z=z[2]; a.w=z[3];
        c.x=z[4]; c.y=z[5]; c.z=z[6]; c.w=z[7];
        p0[0] = a; p0[1] = c;
    }
    out[(size_t)B_ROWS * 8 + r0] = ldv;
}

extern "C" void kernel_launch(void* const* d_in, const int* in_sizes, int n_in,
                              void* d_out, int out_size, void* d_ws, size_t ws_size,
                              hipStream_t stream) {
    const float* x      = (const float*)d_in[0];
    const float* logdet = (const float*)d_in[1];
    const float* bvec   = (const float*)d_in[2];
    const float* logs   = (const float*)d_in[3];
    const float* lg     = (const float*)d_in[4];
    const float* W1     = (const float*)d_in[5];
    const float* b1     = (const float*)d_in[6];
    const float* W2     = (const float*)d_in[7];
    const float* b2     = (const float*)d_in[8];
    const float* Wf     = (const float*)d_in[9];
    const float* bf     = (const float*)d_in[10];
    float* out = (float*)d_out;

    // ws layout (bytes): w2pk[16384] | wfpk[16384] | slots[9*16*64 f32] | bar[4 u32]
    f16*      w2pk  = (f16*)d_ws;
    f16*      wfpk  = w2pk + 8192;
    float*    slots = (float*)(wfpk + 8192);
    unsigned* bar   = (unsigned*)(slots + 9 * 16 * NSLOT);

    // zero slots + bar in one async memset (graph-capture legal)
    hipMemsetAsync(slots, 0, 9 * 16 * NSLOT * sizeof(float) + 4 * sizeof(unsigned),
                   stream);
    pack_weights<<<64, TPB, 0, stream>>>(W2, Wf, w2pk, wfpk);

    void* args[] = {&x, &logdet, &bvec, &logs, &lg, &W1, &b1, &b2, &bf,
                    &w2pk, &wfpk, &out, &slots, &bar};
    hipLaunchKernel(reinterpret_cast<void*>(&flow_fused),
                    dim3(NBLK), dim3(TPB), args, 0, stream);
}

// Round 9
// 149.680 us; speedup vs baseline: 6.3943x; 3.8987x over previous
//
#include <hip/hip_runtime.h>

#define B_ROWS 262144
#define TPB 1024
#define NBLK 256          // B_ROWS / TPB, 1 row/thread; 1 block per CU
#define NSLOT 64          // accumulation slots per stat (bid & 63)
#define NGRP 16           // barrier groups of 16 blocks
#define PADW 32           // 32 dwords = 128 B padding per sync word

// bar layout (dwords): root @0 | gcnt[g] @32+g*32 | gflag[g] @32+512+g*32
#define GC_OFF   32
#define GF_OFF   (32 + NGRP * PADW)
#define BAR_DWORDS (GF_OFF + NGRP * PADW)

typedef _Float16 f16;
typedef __attribute__((ext_vector_type(2))) __fp16 fp16x2_t;  // cvt_pkrtz return type
typedef __attribute__((ext_vector_type(8))) _Float16 f16x8;
typedef __attribute__((ext_vector_type(4))) float f32x4;
typedef __attribute__((ext_vector_type(16))) float f32x16;

__device__ __forceinline__ float fast_tanh(float x) {
    float e = __expf(2.0f * x);
    return 1.0f - 2.0f * __builtin_amdgcn_rcpf(e + 1.0f);
}
__device__ __forceinline__ float pkh(float a, float b) {
    fp16x2_t h = __builtin_amdgcn_cvt_pkrtz(a, b);
    return __builtin_bit_cast(float, h);
}
__device__ __forceinline__ f16x8 mk8(float a, float b, float c, float d) {
    f32x4 v = {a, b, c, d};
    return __builtin_bit_cast(f16x8, v);
}
__device__ __forceinline__ float sx32(float v) { return __shfl_xor(v, 32, 64); }

// Hierarchical grid barrier: group counters -> root -> per-group flags.
// All contended words on private 128B lines. HB: slot writes -sb-> group
// ACQ_REL RMW -> last-in-group root ACQ_REL RMW -> last-overall threadfence
// + flag stores -> spinner ACQUIRE flag load -sb-> slot reads.
__device__ __forceinline__ void gbar(unsigned* bar, unsigned target) {
    __syncthreads();
    if (threadIdx.x == 0) {
        const int g = blockIdx.x >> 4;                 // 16 groups of 16 blocks
        unsigned old = __hip_atomic_fetch_add(bar + GC_OFF + g * PADW, 1u,
                                              __ATOMIC_ACQ_REL,
                                              __HIP_MEMORY_SCOPE_AGENT);
        if (old + 1 == target * (NBLK / NGRP)) {       // last in group
            unsigned ro = __hip_atomic_fetch_add(bar, 1u, __ATOMIC_ACQ_REL,
                                                 __HIP_MEMORY_SCOPE_AGENT);
            if (ro + 1 == target * NGRP) {             // last overall
                __threadfence();
                #pragma unroll
                for (int i = 0; i < NGRP; ++i)
                    __hip_atomic_store(bar + GF_OFF + i * PADW, target,
                                       __ATOMIC_RELAXED,
                                       __HIP_MEMORY_SCOPE_AGENT);
            }
        }
        unsigned* gf = bar + GF_OFF + g * PADW;
        while (__hip_atomic_load(gf, __ATOMIC_RELAXED,
                                 __HIP_MEMORY_SCOPE_AGENT) < target)
            __builtin_amdgcn_s_sleep(16);
        (void)__hip_atomic_load(gf, __ATOMIC_ACQUIRE, __HIP_MEMORY_SCOPE_AGENT);
    }
    __syncthreads();
}

// ---------------------------------------------------------------------------
// Setup: pack W2 / Wf into MFMA A-fragment order (A = W^T), f16.
// ---------------------------------------------------------------------------
__global__ void __launch_bounds__(256)
pack_weights(const float* __restrict__ W2, const float* __restrict__ Wf,
             f16* __restrict__ w2pk, f16* __restrict__ wfpk)
{
    int i = blockIdx.x * 256 + threadIdx.x;     // 0 .. 16383
    int which = i >> 13;
    int t  = i & 8191;
    int j  = t & 7;
    int ln = (t >> 3) & 63;
    int kh = (t >> 9) & 1;
    int L  = t >> 10;
    int k  = kh * 16 + ((ln >> 5) << 3) + j;
    if (which == 0) {
        w2pk[t] = (f16)W2[L * 1024 + k * 32 + (ln & 31)];
    } else {
        int row = ln & 31;
        wfpk[t] = (row < 8) ? (f16)Wf[L * 256 + k * 8 + row] : (f16)0.f;
    }
}

// ---------------------------------------------------------------------------
// Fused persistent kernel: all 8 layers; z, logdet in registers throughout.
// Cross-block stats only via device-scope atomics (slots[9][16][64]).
// ---------------------------------------------------------------------------
__global__ void __launch_bounds__(TPB, 4)
flow_fused(const float* __restrict__ x,    const float* __restrict__ logdet,
           const float* __restrict__ bvec, const float* __restrict__ logs,
           const float* __restrict__ log_gamma,
           const float* __restrict__ W1,   const float* __restrict__ b1,
           const float* __restrict__ b2,   const float* __restrict__ bf,
           const f16* __restrict__ w2pk,   const f16* __restrict__ wfpk,
           float* __restrict__ out,        float* slots,
           unsigned* __restrict__ bar)
{
    const int tid  = threadIdx.x;
    const int bid  = blockIdx.x;
    const int lane = tid & 63;
    const int wid  = tid >> 6;          // 16 waves
    const bool lo  = lane < 32;
    const int slot = bid & (NSLOT - 1);
    const size_t r0 = (size_t)bid * TPB + tid;

    __shared__ float lred[16 * 16];

    // ---- load row + logdet (persistent registers) ----
    float z[8];
    {
        const float4* p0 = reinterpret_cast<const float4*>(x + r0 * 8);
        float4 a = p0[0], c = p0[1];
        z[0]=a.x; z[1]=a.y; z[2]=a.z; z[3]=a.w;
        z[4]=c.x; z[5]=c.y; z[6]=c.z; z[7]=c.w;
    }
    float ldv = logdet[r0];

    // ---- initial partials of x -> slots[0] ----
    {
        float acc[16];
        #pragma unroll
        for (int j = 0; j < 8; ++j) { acc[j] = z[j]; acc[8 + j] = z[j] * z[j]; }
        #pragma unroll
        for (int d = 1; d < 64; d <<= 1) {
            #pragma unroll
            for (int j = 0; j < 16; ++j) acc[j] += __shfl_xor(acc[j], d, 64);
        }
        if (lane == 0) {
            #pragma unroll
            for (int j = 0; j < 16; ++j) lred[wid * 16 + j] = acc[j];
        }
        __syncthreads();
        if (tid < 16) {
            float s = 0.f;
            #pragma unroll
            for (int w = 0; w < 16; ++w) s += lred[w * 16 + tid];
            __hip_atomic_fetch_add(&slots[tid * NSLOT + slot], s,
                                   __ATOMIC_RELAXED, __HIP_MEMORY_SCOPE_AGENT);
        }
    }
    gbar(bar, 1);

    #pragma unroll 1
    for (int L = 0; L < 8; ++L) {
        // ---- stats: wave 0 atomically reads 16x64 slots, butterfly, LDS bcast
        float tot[16];
        {
            float* sl = slots + (size_t)L * (16 * NSLOT);
            if (wid == 0) {
                float a16[16];
                #pragma unroll
                for (int j = 0; j < 16; ++j)
                    a16[j] = __hip_atomic_load(&sl[j * NSLOT + lane],
                                               __ATOMIC_RELAXED,
                                               __HIP_MEMORY_SCOPE_AGENT);
                #pragma unroll
                for (int d = 1; d < 64; d <<= 1) {
                    #pragma unroll
                    for (int j = 0; j < 16; ++j) a16[j] += __shfl_xor(a16[j], d, 64);
                }
                if (lane == 0) {
                    #pragma unroll
                    for (int j = 0; j < 16; ++j) lred[j] = a16[j];
                }
            }
            __syncthreads();
            #pragma unroll
            for (int j = 0; j < 16; ++j) tot[j] = lred[j];
            __syncthreads();   // all reads done before lred reuse
        }

        const float invB = 1.0f / (float)B_ROWS;
        float es[8], beta[8];
        float sum_s = 0.f;
        #pragma unroll
        for (int j = 0; j < 8; ++j) {
            float m = tot[j] * invB;
            float q = tot[8 + j] * invB;
            float v = q - m * m;
            v = v < 0.f ? 0.f : v;
            float li = -(1.0f / 3.0f) * __logf(sqrtf(v) + 1e-6f);
            float s = logs[L * 8 + j] + li;
            s = s < -5.f ? -5.f : (s > 5.f ? 5.f : s);
            es[j]   = __expf(s);
            beta[j] = bvec[L * 8 + j] - m;
            sum_s  += s;
        }
        float gfac[4];
        #pragma unroll
        for (int j = 0; j < 4; ++j) {
            float lg = log_gamma[L * 4 + j];
            lg = lg < -5.f ? -5.f : (lg > 5.f ? 5.f : lg);
            gfac[j] = __expf(lg);
        }

        // ---- actnorm ----
        #pragma unroll
        for (int j = 0; j < 8; ++j)
            z[j] = (z[j] + beta[j]) * es[j];

        // ---- W1: 4 -> 32, fp32 VALU ----
        const float* w1  = W1 + L * (4 * 32);
        const float* vb1 = b1 + L * 32;
        const float* vb2 = b2 + L * 32;
        const float* vbf = bf + L * 8;

        float h1[32];
        #pragma unroll
        for (int w = 0; w < 32; ++w) {
            float t = vb1[w];
            #pragma unroll
            for (int k = 0; k < 4; ++k)
                t += z[k] * w1[k * 32 + w];
            h1[w] = t > 0.f ? t : 0.f;
        }

        // ---- pack h1 -> f16 pairs; W2 B-fragments ----
        float hp[16];
        #pragma unroll
        for (int c = 0; c < 16; ++c) hp[c] = pkh(h1[2 * c], h1[2 * c + 1]);
        float Sv[16];
        #pragma unroll
        for (int c = 0; c < 16; ++c) Sv[c] = sx32(hp[c]);

        f16x8 B00 = mk8(lo?hp[0]:Sv[4],  lo?hp[1]:Sv[5],  lo?hp[2]:Sv[6],  lo?hp[3]:Sv[7]);
        f16x8 B01 = mk8(lo?hp[8]:Sv[12], lo?hp[9]:Sv[13], lo?hp[10]:Sv[14],lo?hp[11]:Sv[15]);
        f16x8 B10 = mk8(lo?Sv[0]:hp[4],  lo?Sv[1]:hp[5],  lo?Sv[2]:hp[6],  lo?Sv[3]:hp[7]);
        f16x8 B11 = mk8(lo?Sv[8]:hp[12], lo?Sv[9]:hp[13], lo?Sv[10]:hp[14],lo?Sv[11]:hp[15]);

        const f16x8* w2p = reinterpret_cast<const f16x8*>(w2pk);
        f16x8 A0 = w2p[(L * 2 + 0) * 64 + lane];
        f16x8 A1 = w2p[(L * 2 + 1) * 64 + lane];

        f32x16 d0 = {}, d1 = {};
        d0 = __builtin_amdgcn_mfma_f32_32x32x16_f16(A0, B00, d0, 0, 0, 0);
        d0 = __builtin_amdgcn_mfma_f32_32x32x16_f16(A1, B01, d0, 0, 0, 0);
        d1 = __builtin_amdgcn_mfma_f32_32x32x16_f16(A0, B10, d1, 0, 0, 0);
        d1 = __builtin_amdgcn_mfma_f32_32x32x16_f16(A1, B11, d1, 0, 0, 0);

        float h2g0[16], h2g1[16];
        #pragma unroll
        for (int r = 0; r < 16; ++r) {
            int wlo = (r & 3) + 8 * (r >> 2);
            float bsel = lo ? vb2[wlo] : vb2[wlo + 4];
            float a = d0[r] + bsel; h2g0[r] = a > 0.f ? a : 0.f;
            float b = d1[r] + bsel; h2g1[r] = b > 0.f ? b : 0.f;
        }

        float P0[8], P1[8], X0[8], X1[8];
        #pragma unroll
        for (int c = 0; c < 8; ++c) {
            P0[c] = pkh(h2g0[2 * c], h2g0[2 * c + 1]);
            P1[c] = pkh(h2g1[2 * c], h2g1[2 * c + 1]);
        }
        #pragma unroll
        for (int c = 0; c < 8; ++c) { X0[c] = sx32(P0[c]); X1[c] = sx32(P1[c]); }

        f16x8 C00 = mk8(lo?P0[0]:X0[2], lo?P0[1]:X0[3], lo?X0[0]:P0[2], lo?X0[1]:P0[3]);
        f16x8 C01 = mk8(lo?P0[4]:X0[6], lo?P0[5]:X0[7], lo?X0[4]:P0[6], lo?X0[5]:P0[7]);
        f16x8 C10 = mk8(lo?P1[0]:X1[2], lo?P1[1]:X1[3], lo?X1[0]:P1[2], lo?X1[1]:P1[3]);
        f16x8 C11 = mk8(lo?P1[4]:X1[6], lo?P1[5]:X1[7], lo?X1[4]:P1[6], lo?X1[5]:P1[7]);

        const f16x8* wfp = reinterpret_cast<const f16x8*>(wfpk);
        f16x8 F0 = wfp[(L * 2 + 0) * 64 + lane];
        f16x8 F1 = wfp[(L * 2 + 1) * 64 + lane];

        f32x16 e0 = {}, e1 = {};
        e0 = __builtin_amdgcn_mfma_f32_32x32x16_f16(F0, C00, e0, 0, 0, 0);
        e0 = __builtin_amdgcn_mfma_f32_32x32x16_f16(F1, C01, e0, 0, 0, 0);
        e1 = __builtin_amdgcn_mfma_f32_32x32x16_f16(F0, C10, e1, 0, 0, 0);
        e1 = __builtin_amdgcn_mfma_f32_32x32x16_f16(F1, C11, e1, 0, 0, 0);

        float h3[8];
        #pragma unroll
        for (int r = 0; r < 4; ++r) {
            float s0 = sx32(e0[r]);
            float s1 = sx32(e1[r]);
            h3[r]     = (lo ? e0[r] : s1) + vbf[r];
            h3[r + 4] = (lo ? s0 : e1[r]) + vbf[r + 4];
        }

        // ---- coupling epilogue + permutation + next-layer partials ----
        float nacc[16];
        {
            float ldl = 0.f;
            float nz[8];
            #pragma unroll
            for (int j = 0; j < 4; ++j) {
                float sc = 0.6f * fast_tanh(h3[2 * j + 1]);
                float sh = gfac[j] * fast_tanh(h3[2 * j]);
                float z2 = z[4 + j];
                z2 = z2 + sc * z2 + sh;
                ldl += __logf(1.0f + sc);
                nz[3 - j] = z2;      // reversed: out[3-j] = z2_j
                nz[7 - j] = z[j];    // reversed: out[7-j] = z1_j
            }
            ldv += sum_s + ldl;
            #pragma unroll
            for (int j = 0; j < 8; ++j) {
                z[j] = nz[j];
                nacc[j]     = nz[j];
                nacc[8 + j] = nz[j] * nz[j];
            }
        }

        if (L < 7) {
            #pragma unroll
            for (int d = 1; d < 64; d <<= 1) {
                #pragma unroll
                for (int j = 0; j < 16; ++j) nacc[j] += __shfl_xor(nacc[j], d, 64);
            }
            if (lane == 0) {
                #pragma unroll
                for (int j = 0; j < 16; ++j) lred[wid * 16 + j] = nacc[j];
            }
            __syncthreads();
            if (tid < 16) {
                float s = 0.f;
                #pragma unroll
                for (int w = 0; w < 16; ++w) s += lred[w * 16 + tid];
                __hip_atomic_fetch_add(&slots[(size_t)(L + 1) * (16 * NSLOT) +
                                              tid * NSLOT + slot], s,
                                       __ATOMIC_RELAXED, __HIP_MEMORY_SCOPE_AGENT);
            }
            gbar(bar, (unsigned)(L + 2));
        }
    }

    // ---- store outputs: z (B,8) then ld (B,1) ----
    {
        float4* p0 = reinterpret_cast<float4*>(out + r0 * 8);
        float4 a, c;
        a.x=z[0]; a.y=z[1]; a.z=z[2]; a.w=z[3];
        c.x=z[4]; c.y=z[5]; c.z=z[6]; c.w=z[7];
        p0[0] = a; p0[1] = c;
    }
    out[(size_t)B_ROWS * 8 + r0] = ldv;
}

extern "C" void kernel_launch(void* const* d_in, const int* in_sizes, int n_in,
                              void* d_out, int out_size, void* d_ws, size_t ws_size,
                              hipStream_t stream) {
    const float* x      = (const float*)d_in[0];
    const float* logdet = (const float*)d_in[1];
    const float* bvec   = (const float*)d_in[2];
    const float* logs   = (const float*)d_in[3];
    const float* lg     = (const float*)d_in[4];
    const float* W1     = (const float*)d_in[5];
    const float* b1     = (const float*)d_in[6];
    const float* W2     = (const float*)d_in[7];
    const float* b2     = (const float*)d_in[8];
    const float* Wf     = (const float*)d_in[9];
    const float* bf     = (const float*)d_in[10];
    float* out = (float*)d_out;

    // ws layout: w2pk[16384 B] | wfpk[16384 B] | slots[9*16*64 f32] | bar[BAR_DWORDS u32]
    f16*      w2pk  = (f16*)d_ws;
    f16*      wfpk  = w2pk + 8192;
    float*    slots = (float*)(wfpk + 8192);
    unsigned* bar   = (unsigned*)(slots + 9 * 16 * NSLOT);

    hipMemsetAsync(slots, 0,
                   9 * 16 * NSLOT * sizeof(float) + BAR_DWORDS * sizeof(unsigned),
                   stream);
    pack_weights<<<64, 256, 0, stream>>>(W2, Wf, w2pk, wfpk);

    void* args[] = {&x, &logdet, &bvec, &logs, &lg, &W1, &b1, &b2, &bf,
                    &w2pk, &wfpk, &out, &slots, &bar};
    hipLaunchKernel(reinterpret_cast<void*>(&flow_fused),
                    dim3(NBLK), dim3(TPB), args, 0, stream);
}

// Round 10
// 136.017 us; speedup vs baseline: 7.0366x; 1.1005x over previous
//
#include <hip/hip_runtime.h>

#define B_ROWS 262144
#define TPB 1024
#define NBLK 256          // B_ROWS / TPB, 1 row/thread; 1 block per CU
#define NSLOT 64          // accumulation slots per stat (bid & 63)
#define NGRP 16           // barrier groups of 16 blocks
#define PADW 32           // 32 dwords = 128 B padding per sync word

// bar layout (dwords): root @0 | gcnt[g] @32+g*32 | gflag[g] @32+512+g*32
#define GC_OFF   32
#define GF_OFF   (32 + NGRP * PADW)
#define BAR_DWORDS (GF_OFF + NGRP * PADW)

typedef _Float16 f16;
typedef __attribute__((ext_vector_type(2))) __fp16 fp16x2_t;  // cvt_pkrtz return type
typedef __attribute__((ext_vector_type(8))) _Float16 f16x8;
typedef __attribute__((ext_vector_type(4))) float f32x4;
typedef __attribute__((ext_vector_type(16))) float f32x16;
typedef __attribute__((ext_vector_type(2))) unsigned u32x2;

__device__ __forceinline__ float fast_tanh(float x) {
    float e = __expf(2.0f * x);
    return 1.0f - 2.0f * __builtin_amdgcn_rcpf(e + 1.0f);
}
__device__ __forceinline__ float pkh(float a, float b) {
    fp16x2_t h = __builtin_amdgcn_cvt_pkrtz(a, b);
    return __builtin_bit_cast(float, h);
}
__device__ __forceinline__ f16x8 mk8(float a, float b, float c, float d) {
    f32x4 v = {a, b, c, d};
    return __builtin_bit_cast(f16x8, v);
}
__device__ __forceinline__ float bcf(unsigned u) { return __builtin_bit_cast(float, u); }
// v_permlane32_swap_b32: out[0] = {a.lo32lanes, b.lo32lanes}, out[1] = {a.hi, b.hi}
__device__ __forceinline__ u32x2 pls(float a, float b) {
    return __builtin_amdgcn_permlane32_swap(
        __builtin_bit_cast(unsigned, a), __builtin_bit_cast(unsigned, b),
        false, false);
}

// Hierarchical grid barrier (unchanged from R9 except sleep granularity).
__device__ __forceinline__ void gbar(unsigned* bar, unsigned target) {
    __syncthreads();
    if (threadIdx.x == 0) {
        const int g = blockIdx.x >> 4;
        unsigned old = __hip_atomic_fetch_add(bar + GC_OFF + g * PADW, 1u,
                                              __ATOMIC_ACQ_REL,
                                              __HIP_MEMORY_SCOPE_AGENT);
        if (old + 1 == target * (NBLK / NGRP)) {
            unsigned ro = __hip_atomic_fetch_add(bar, 1u, __ATOMIC_ACQ_REL,
                                                 __HIP_MEMORY_SCOPE_AGENT);
            if (ro + 1 == target * NGRP) {
                __threadfence();
                #pragma unroll
                for (int i = 0; i < NGRP; ++i)
                    __hip_atomic_store(bar + GF_OFF + i * PADW, target,
                                       __ATOMIC_RELAXED,
                                       __HIP_MEMORY_SCOPE_AGENT);
            }
        }
        unsigned* gf = bar + GF_OFF + g * PADW;
        while (__hip_atomic_load(gf, __ATOMIC_RELAXED,
                                 __HIP_MEMORY_SCOPE_AGENT) < target)
            __builtin_amdgcn_s_sleep(2);
        (void)__hip_atomic_load(gf, __ATOMIC_ACQUIRE, __HIP_MEMORY_SCOPE_AGENT);
    }
    __syncthreads();
}

// ---------------------------------------------------------------------------
// Setup: pack W1 / W2 / Wf into MFMA A-fragment order (A = W^T), f16.
// w2pk/wfpk: t=((L*2+kh)*64+ln)*8+j -> W[k=kh*16+(ln>>5)*8+j][ln&31]
// w1pk:      t=((L)*64+ln)*8+j      -> k=(ln>>5)*8+j<4 ? W1[L][k][ln&31] : 0
// ---------------------------------------------------------------------------
__global__ void __launch_bounds__(256)
pack_weights(const float* __restrict__ W1, const float* __restrict__ W2,
             const float* __restrict__ Wf,
             f16* __restrict__ w1pk, f16* __restrict__ w2pk, f16* __restrict__ wfpk)
{
    int i = blockIdx.x * 256 + threadIdx.x;     // 0 .. 20479
    if (i < 16384) {
        int which = i >> 13;
        int t  = i & 8191;
        int j  = t & 7;
        int ln = (t >> 3) & 63;
        int kh = (t >> 9) & 1;
        int L  = t >> 10;
        int k  = kh * 16 + ((ln >> 5) << 3) + j;
        if (which == 0) {
            w2pk[t] = (f16)W2[L * 1024 + k * 32 + (ln & 31)];
        } else {
            int row = ln & 31;
            wfpk[t] = (row < 8) ? (f16)Wf[L * 256 + k * 8 + row] : (f16)0.f;
        }
    } else {
        int t  = i - 16384;                     // 0 .. 4095
        int j  = t & 7;
        int ln = (t >> 3) & 63;
        int L  = t >> 9;
        int k  = ((ln >> 5) << 3) + j;
        w1pk[t] = (k < 4) ? (f16)W1[L * 128 + k * 32 + (ln & 31)] : (f16)0.f;
    }
}

// ---------------------------------------------------------------------------
// Fused persistent kernel: all 8 layers; z, logdet in registers throughout.
// ---------------------------------------------------------------------------
__global__ void __launch_bounds__(TPB, 4)
flow_fused(const float* __restrict__ x,    const float* __restrict__ logdet,
           const float* __restrict__ bvec, const float* __restrict__ logs,
           const float* __restrict__ log_gamma,
           const float* __restrict__ b1,   const float* __restrict__ b2,
           const float* __restrict__ bf,
           const f16* __restrict__ w1pk,   const f16* __restrict__ w2pk,
           const f16* __restrict__ wfpk,
           float* __restrict__ out,        float* slots,
           unsigned* __restrict__ bar)
{
    const int tid  = threadIdx.x;
    const int bid  = blockIdx.x;
    const int lane = tid & 63;
    const int wid  = tid >> 6;          // 16 waves
    const bool lo  = lane < 32;
    const int slot = bid & (NSLOT - 1);
    // bit-reversed low-4 lane bits: component index after payload-halving butterfly
    const int br = ((lane & 1) << 3) | ((lane & 2) << 1) | ((lane & 4) >> 1) | ((lane & 8) >> 3);
    const size_t r0 = (size_t)bid * TPB + tid;

    __shared__ float lred[16 * 16];

    // ---- load row + logdet (persistent registers) ----
    float z[8];
    {
        const float4* p0 = reinterpret_cast<const float4*>(x + r0 * 8);
        float4 a = p0[0], c = p0[1];
        z[0]=a.x; z[1]=a.y; z[2]=a.z; z[3]=a.w;
        z[4]=c.x; z[5]=c.y; z[6]=c.z; z[7]=c.w;
    }
    float ldv = logdet[r0];

    // ---- initial partials of x -> slots[0] (payload-halving butterfly) ----
    {
        float acc[16];
        #pragma unroll
        for (int j = 0; j < 8; ++j) { acc[j] = z[j]; acc[8 + j] = z[j] * z[j]; }
        #pragma unroll
        for (int i = 0; i < 8; ++i) {
            float snd = (lane & 1) ? acc[i] : acc[8 + i];
            float kp  = (lane & 1) ? acc[8 + i] : acc[i];
            acc[i] = kp + __shfl_xor(snd, 1, 64);
        }
        #pragma unroll
        for (int i = 0; i < 4; ++i) {
            float snd = (lane & 2) ? acc[i] : acc[4 + i];
            float kp  = (lane & 2) ? acc[4 + i] : acc[i];
            acc[i] = kp + __shfl_xor(snd, 2, 64);
        }
        #pragma unroll
        for (int i = 0; i < 2; ++i) {
            float snd = (lane & 4) ? acc[i] : acc[2 + i];
            float kp  = (lane & 4) ? acc[2 + i] : acc[i];
            acc[i] = kp + __shfl_xor(snd, 4, 64);
        }
        {
            float snd = (lane & 8) ? acc[0] : acc[1];
            float kp  = (lane & 8) ? acc[1] : acc[0];
            acc[0] = kp + __shfl_xor(snd, 8, 64);
        }
        acc[0] += __shfl_xor(acc[0], 16, 64);
        acc[0] += __shfl_xor(acc[0], 32, 64);
        if (lane < 16) lred[wid * 16 + br] = acc[0];
        __syncthreads();
        if (tid < 16) {
            float s = 0.f;
            #pragma unroll
            for (int w = 0; w < 16; ++w) s += lred[w * 16 + tid];
            __hip_atomic_fetch_add(&slots[tid * NSLOT + slot], s,
                                   __ATOMIC_RELAXED, __HIP_MEMORY_SCOPE_AGENT);
        }
    }
    gbar(bar, 1);

    const f16x8* w1p = reinterpret_cast<const f16x8*>(w1pk);
    const f16x8* w2p = reinterpret_cast<const f16x8*>(w2pk);
    const f16x8* wfp = reinterpret_cast<const f16x8*>(wfpk);

    #pragma unroll 1
    for (int L = 0; L < 8; ++L) {
        // hoist A-fragment loads (latency hides under the stats read)
        const f16x8 W1A = w1p[L * 64 + lane];
        const f16x8 A0  = w2p[(L * 2 + 0) * 64 + lane];
        const f16x8 A1  = w2p[(L * 2 + 1) * 64 + lane];
        const f16x8 F0  = wfp[(L * 2 + 0) * 64 + lane];
        const f16x8 F1  = wfp[(L * 2 + 1) * 64 + lane];

        // ---- stats: wave 0 reads 16x64 slots, butterfly, LDS bcast ----
        float tot[16];
        {
            float* sl = slots + (size_t)L * (16 * NSLOT);
            if (wid == 0) {
                float a16[16];
                #pragma unroll
                for (int j = 0; j < 16; ++j)
                    a16[j] = __hip_atomic_load(&sl[j * NSLOT + lane],
                                               __ATOMIC_RELAXED,
                                               __HIP_MEMORY_SCOPE_AGENT);
                #pragma unroll
                for (int d = 1; d < 64; d <<= 1) {
                    #pragma unroll
                    for (int j = 0; j < 16; ++j) a16[j] += __shfl_xor(a16[j], d, 64);
                }
                if (lane == 0) {
                    #pragma unroll
                    for (int j = 0; j < 16; ++j) lred[j] = a16[j];
                }
            }
            __syncthreads();
            #pragma unroll
            for (int j = 0; j < 16; ++j) tot[j] = lred[j];
            __syncthreads();   // all reads done before lred reuse
        }

        const float invB = 1.0f / (float)B_ROWS;
        float es[8], beta[8];
        float sum_s = 0.f;
        #pragma unroll
        for (int j = 0; j < 8; ++j) {
            float m = tot[j] * invB;
            float q = tot[8 + j] * invB;
            float v = q - m * m;
            v = v < 0.f ? 0.f : v;
            float li = -(1.0f / 3.0f) * __logf(sqrtf(v) + 1e-6f);
            float s = logs[L * 8 + j] + li;
            s = s < -5.f ? -5.f : (s > 5.f ? 5.f : s);
            es[j]   = __expf(s);
            beta[j] = bvec[L * 8 + j] - m;
            sum_s  += s;
        }
        float gfac[4];
        #pragma unroll
        for (int j = 0; j < 4; ++j) {
            float lg = log_gamma[L * 4 + j];
            lg = lg < -5.f ? -5.f : (lg > 5.f ? 5.f : lg);
            gfac[j] = __expf(lg);
        }

        // ---- actnorm ----
        #pragma unroll
        for (int j = 0; j < 8; ++j)
            z[j] = (z[j] + beta[j]) * es[j];

        const float* vb1 = b1 + L * 32;
        const float* vb2 = b2 + L * 32;
        const float* vbf = bf + L * 8;

        // ---- W1 via MFMA: h1^T = W1^T(padded K=16) @ z1^T ----
        float zp0 = pkh(z[0], z[1]);
        float zp1 = pkh(z[2], z[3]);
        u32x2 s0 = pls(zp0, 0.f);
        u32x2 s1 = pls(zp1, 0.f);
        f16x8 Z0 = mk8(bcf(s0[0]), bcf(s1[0]), 0.f, 0.f);   // rows 0-31
        f16x8 Z1 = mk8(bcf(s0[1]), bcf(s1[1]), 0.f, 0.f);   // rows 32-63

        f32x16 g0 = {}, g1 = {};
        g0 = __builtin_amdgcn_mfma_f32_32x32x16_f16(W1A, Z0, g0, 0, 0, 0);
        g1 = __builtin_amdgcn_mfma_f32_32x32x16_f16(W1A, Z1, g1, 0, 0, 0);

        // bias + relu + pack to f16 pairs (q layout: C-layout dim pairs)
        float qg0[8], qg1[8];
        {
            float h0[16], h1v[16];
            #pragma unroll
            for (int r = 0; r < 16; ++r) {
                int wlo = (r & 3) + 8 * (r >> 2);
                float bsel = lo ? vb1[wlo] : vb1[wlo + 4];
                float a = g0[r] + bsel; h0[r]  = a > 0.f ? a : 0.f;
                float b = g1[r] + bsel; h1v[r] = b > 0.f ? b : 0.f;
            }
            #pragma unroll
            for (int c = 0; c < 8; ++c) {
                qg0[c] = pkh(h0[2 * c], h0[2 * c + 1]);
                qg1[c] = pkh(h1v[2 * c], h1v[2 * c + 1]);
            }
        }

        // ---- W2 B-frags via permlane32_swap ----
        u32x2 pA = pls(qg0[0], qg0[2]);
        u32x2 pB = pls(qg0[1], qg0[3]);
        u32x2 pC = pls(qg0[4], qg0[6]);
        u32x2 pD = pls(qg0[5], qg0[7]);
        f16x8 B00 = mk8(bcf(pA[0]), bcf(pB[0]), bcf(pA[1]), bcf(pB[1]));
        f16x8 B01 = mk8(bcf(pC[0]), bcf(pD[0]), bcf(pC[1]), bcf(pD[1]));
        pA = pls(qg1[0], qg1[2]);
        pB = pls(qg1[1], qg1[3]);
        pC = pls(qg1[4], qg1[6]);
        pD = pls(qg1[5], qg1[7]);
        f16x8 B10 = mk8(bcf(pA[0]), bcf(pB[0]), bcf(pA[1]), bcf(pB[1]));
        f16x8 B11 = mk8(bcf(pC[0]), bcf(pD[0]), bcf(pC[1]), bcf(pD[1]));

        f32x16 d0 = {}, d1 = {};
        d0 = __builtin_amdgcn_mfma_f32_32x32x16_f16(A0, B00, d0, 0, 0, 0);
        d0 = __builtin_amdgcn_mfma_f32_32x32x16_f16(A1, B01, d0, 0, 0, 0);
        d1 = __builtin_amdgcn_mfma_f32_32x32x16_f16(A0, B10, d1, 0, 0, 0);
        d1 = __builtin_amdgcn_mfma_f32_32x32x16_f16(A1, B11, d1, 0, 0, 0);

        // ---- + b2, relu, pack ----
        float P0[8], P1[8];
        {
            float h2g0[16], h2g1[16];
            #pragma unroll
            for (int r = 0; r < 16; ++r) {
                int wlo = (r & 3) + 8 * (r >> 2);
                float bsel = lo ? vb2[wlo] : vb2[wlo + 4];
                float a = d0[r] + bsel; h2g0[r] = a > 0.f ? a : 0.f;
                float b = d1[r] + bsel; h2g1[r] = b > 0.f ? b : 0.f;
            }
            #pragma unroll
            for (int c = 0; c < 8; ++c) {
                P0[c] = pkh(h2g0[2 * c], h2g0[2 * c + 1]);
                P1[c] = pkh(h2g1[2 * c], h2g1[2 * c + 1]);
            }
        }

        // ---- Wf C-frags via permlane32_swap ----
        u32x2 pE = pls(P0[0], P0[2]);
        u32x2 pF = pls(P0[1], P0[3]);
        u32x2 pG = pls(P0[4], P0[6]);
        u32x2 pH = pls(P0[5], P0[7]);
        f16x8 C00 = mk8(bcf(pE[0]), bcf(pF[0]), bcf(pE[1]), bcf(pF[1]));
        f16x8 C01 = mk8(bcf(pG[0]), bcf(pH[0]), bcf(pG[1]), bcf(pH[1]));
        pE = pls(P1[0], P1[2]);
        pF = pls(P1[1], P1[3]);
        pG = pls(P1[4], P1[6]);
        pH = pls(P1[5], P1[7]);
        f16x8 C10 = mk8(bcf(pE[0]), bcf(pF[0]), bcf(pE[1]), bcf(pF[1]));
        f16x8 C11 = mk8(bcf(pG[0]), bcf(pH[0]), bcf(pG[1]), bcf(pH[1]));

        f32x16 e0 = {}, e1 = {};
        e0 = __builtin_amdgcn_mfma_f32_32x32x16_f16(F0, C00, e0, 0, 0, 0);
        e0 = __builtin_amdgcn_mfma_f32_32x32x16_f16(F1, C01, e0, 0, 0, 0);
        e1 = __builtin_amdgcn_mfma_f32_32x32x16_f16(F0, C10, e1, 0, 0, 0);
        e1 = __builtin_amdgcn_mfma_f32_32x32x16_f16(F1, C11, e1, 0, 0, 0);

        // ---- gather own row's h3 via permlane32_swap ----
        float h3[8];
        #pragma unroll
        for (int r = 0; r < 4; ++r) {
            u32x2 pe = pls(e0[r], e1[r]);
            h3[r]     = bcf(pe[0]) + vbf[r];
            h3[r + 4] = bcf(pe[1]) + vbf[r + 4];
        }

        // ---- coupling epilogue + permutation + next-layer partials ----
        float nacc[16];
        {
            float ldl = 0.f;
            float nz[8];
            #pragma unroll
            for (int j = 0; j < 4; ++j) {
                float sc = 0.6f * fast_tanh(h3[2 * j + 1]);
                float sh = gfac[j] * fast_tanh(h3[2 * j]);
                float z2 = z[4 + j];
                z2 = z2 + sc * z2 + sh;
                ldl += __logf(1.0f + sc);
                nz[3 - j] = z2;      // reversed: out[3-j] = z2_j
                nz[7 - j] = z[j];    // reversed: out[7-j] = z1_j
            }
            ldv += sum_s + ldl;
            #pragma unroll
            for (int j = 0; j < 8; ++j) {
                z[j] = nz[j];
                nacc[j]     = nz[j];
                nacc[8 + j] = nz[j] * nz[j];
            }
        }

        if (L < 7) {
            #pragma unroll
            for (int i = 0; i < 8; ++i) {
                float snd = (lane & 1) ? nacc[i] : nacc[8 + i];
                float kp  = (lane & 1) ? nacc[8 + i] : nacc[i];
                nacc[i] = kp + __shfl_xor(snd, 1, 64);
            }
            #pragma unroll
            for (int i = 0; i < 4; ++i) {
                float snd = (lane & 2) ? nacc[i] : nacc[4 + i];
                float kp  = (lane & 2) ? nacc[4 + i] : nacc[i];
                nacc[i] = kp + __shfl_xor(snd, 2, 64);
            }
            #pragma unroll
            for (int i = 0; i < 2; ++i) {
                float snd = (lane & 4) ? nacc[i] : nacc[2 + i];
                float kp  = (lane & 4) ? nacc[2 + i] : nacc[i];
                nacc[i] = kp + __shfl_xor(snd, 4, 64);
            }
            {
                float snd = (lane & 8) ? nacc[0] : nacc[1];
                float kp  = (lane & 8) ? nacc[1] : nacc[0];
                nacc[0] = kp + __shfl_xor(snd, 8, 64);
            }
            nacc[0] += __shfl_xor(nacc[0], 16, 64);
            nacc[0] += __shfl_xor(nacc[0], 32, 64);
            if (lane < 16) lred[wid * 16 + br] = nacc[0];
            __syncthreads();
            if (tid < 16) {
                float s = 0.f;
                #pragma unroll
                for (int w = 0; w < 16; ++w) s += lred[w * 16 + tid];
                __hip_atomic_fetch_add(&slots[(size_t)(L + 1) * (16 * NSLOT) +
                                              tid * NSLOT + slot], s,
                                       __ATOMIC_RELAXED, __HIP_MEMORY_SCOPE_AGENT);
            }
            gbar(bar, (unsigned)(L + 2));
        }
    }

    // ---- store outputs: z (B,8) then ld (B,1) ----
    {
        float4* p0 = reinterpret_cast<float4*>(out + r0 * 8);
        float4 a, c;
        a.x=z[0]; a.y=z[1]; a.z=z[2]; a.w=z[3];
        c.x=z[4]; c.y=z[5]; c.z=z[6]; c.w=z[7];
        p0[0] = a; p0[1] = c;
    }
    out[(size_t)B_ROWS * 8 + r0] = ldv;
}

extern "C" void kernel_launch(void* const* d_in, const int* in_sizes, int n_in,
                              void* d_out, int out_size, void* d_ws, size_t ws_size,
                              hipStream_t stream) {
    const float* x      = (const float*)d_in[0];
    const float* logdet = (const float*)d_in[1];
    const float* bvec   = (const float*)d_in[2];
    const float* logs   = (const float*)d_in[3];
    const float* lg     = (const float*)d_in[4];
    const float* W1     = (const float*)d_in[5];
    const float* b1     = (const float*)d_in[6];
    const float* W2     = (const float*)d_in[7];
    const float* b2     = (const float*)d_in[8];
    const float* Wf     = (const float*)d_in[9];
    const float* bf     = (const float*)d_in[10];
    float* out = (float*)d_out;

    // ws layout: w1pk[8192 B] | w2pk[16384 B] | wfpk[16384 B]
    //            | slots[9*16*64 f32] | bar[BAR_DWORDS u32]
    f16*      w1pk  = (f16*)d_ws;
    f16*      w2pk  = w1pk + 4096;
    f16*      wfpk  = w2pk + 8192;
    float*    slots = (float*)(wfpk + 8192);
    unsigned* bar   = (unsigned*)(slots + 9 * 16 * NSLOT);

    hipMemsetAsync(slots, 0,
                   9 * 16 * NSLOT * sizeof(float) + BAR_DWORDS * sizeof(unsigned),
                   stream);
    pack_weights<<<80, 256, 0, stream>>>(W1, W2, Wf, w1pk, w2pk, wfpk);

    void* args[] = {&x, &logdet, &bvec, &logs, &lg, &b1, &b2, &bf,
                    &w1pk, &w2pk, &wfpk, &out, &slots, &bar};
    hipLaunchKernel(reinterpret_cast<void*>(&flow_fused),
                    dim3(NBLK), dim3(TPB), args, 0, stream);
}

// Round 11
// 128.316 us; speedup vs baseline: 7.4589x; 1.0600x over previous
//
#include <hip/hip_runtime.h>

#define B_ROWS 262144
#define TPB 1024
#define NBLK 256          // B_ROWS / TPB, 1 row/thread; 1 block per CU
#define NSLOT 64          // accumulation slots per stat (bid & 63)
#define NGRP 16           // barrier groups of 16 blocks
#define PADW 32           // 32 dwords = 128 B padding per sync/slot word

// slots: [9 layers][16 stats][64 slots], each padded to its own 128B line
#define SLOT_DW (16 * NSLOT * PADW)          // dwords per layer
#define SLOTS_TOTAL_DW (9 * SLOT_DW)

// bar layout (dwords): root @0 | gcnt[g] @32+g*32 | gflag[g] @32+512+g*32
#define GC_OFF   32
#define GF_OFF   (32 + NGRP * PADW)
#define BAR_DWORDS (GF_OFF + NGRP * PADW)

#define ZERO_DWORDS (SLOTS_TOTAL_DW + BAR_DWORDS)

typedef _Float16 f16;
typedef __attribute__((ext_vector_type(2))) __fp16 fp16x2_t;  // cvt_pkrtz return type
typedef __attribute__((ext_vector_type(8))) _Float16 f16x8;
typedef __attribute__((ext_vector_type(4))) float f32x4;
typedef __attribute__((ext_vector_type(16))) float f32x16;
typedef __attribute__((ext_vector_type(2))) unsigned u32x2;

__device__ __forceinline__ float fast_tanh(float x) {
    float e = __expf(2.0f * x);
    return 1.0f - 2.0f * __builtin_amdgcn_rcpf(e + 1.0f);
}
__device__ __forceinline__ float pkh(float a, float b) {
    fp16x2_t h = __builtin_amdgcn_cvt_pkrtz(a, b);
    return __builtin_bit_cast(float, h);
}
__device__ __forceinline__ f16x8 mk8(float a, float b, float c, float d) {
    f32x4 v = {a, b, c, d};
    return __builtin_bit_cast(f16x8, v);
}
__device__ __forceinline__ float bcf(unsigned u) { return __builtin_bit_cast(float, u); }
// v_permlane32_swap_b32: out[0] = {a.lo32lanes, b.lo32lanes}, out[1] = {a.hi, b.hi}
__device__ __forceinline__ u32x2 pls(float a, float b) {
    return __builtin_amdgcn_permlane32_swap(
        __builtin_bit_cast(unsigned, a), __builtin_bit_cast(unsigned, b),
        false, false);
}

// Hierarchical grid barrier (R9 design).
__device__ __forceinline__ void gbar(unsigned* bar, unsigned target) {
    __syncthreads();
    if (threadIdx.x == 0) {
        const int g = blockIdx.x >> 4;
        unsigned old = __hip_atomic_fetch_add(bar + GC_OFF + g * PADW, 1u,
                                              __ATOMIC_ACQ_REL,
                                              __HIP_MEMORY_SCOPE_AGENT);
        if (old + 1 == target * (NBLK / NGRP)) {
            unsigned ro = __hip_atomic_fetch_add(bar, 1u, __ATOMIC_ACQ_REL,
                                                 __HIP_MEMORY_SCOPE_AGENT);
            if (ro + 1 == target * NGRP) {
                __threadfence();
                #pragma unroll
                for (int i = 0; i < NGRP; ++i)
                    __hip_atomic_store(bar + GF_OFF + i * PADW, target,
                                       __ATOMIC_RELAXED,
                                       __HIP_MEMORY_SCOPE_AGENT);
            }
        }
        unsigned* gf = bar + GF_OFF + g * PADW;
        while (__hip_atomic_load(gf, __ATOMIC_RELAXED,
                                 __HIP_MEMORY_SCOPE_AGENT) < target)
            __builtin_amdgcn_s_sleep(2);
        (void)__hip_atomic_load(gf, __ATOMIC_ACQUIRE, __HIP_MEMORY_SCOPE_AGENT);
    }
    __syncthreads();
}

// ---------------------------------------------------------------------------
// Setup: pack W1 / W2 / Wf into MFMA A-fragment order (A = W^T), f16,
// and zero the slots + barrier region (replaces hipMemsetAsync).
// ---------------------------------------------------------------------------
#define PKBLK 80
__global__ void __launch_bounds__(256)
pack_weights(const float* __restrict__ W1, const float* __restrict__ W2,
             const float* __restrict__ Wf,
             f16* __restrict__ w1pk, f16* __restrict__ w2pk, f16* __restrict__ wfpk,
             float* __restrict__ zbase)
{
    int i = blockIdx.x * 256 + threadIdx.x;     // 0 .. 20479
    if (i < 16384) {
        int which = i >> 13;
        int t  = i & 8191;
        int j  = t & 7;
        int ln = (t >> 3) & 63;
        int kh = (t >> 9) & 1;
        int L  = t >> 10;
        int k  = kh * 16 + ((ln >> 5) << 3) + j;
        if (which == 0) {
            w2pk[t] = (f16)W2[L * 1024 + k * 32 + (ln & 31)];
        } else {
            int row = ln & 31;
            wfpk[t] = (row < 8) ? (f16)Wf[L * 256 + k * 8 + row] : (f16)0.f;
        }
    } else {
        int t  = i - 16384;                     // 0 .. 4095
        int j  = t & 7;
        int ln = (t >> 3) & 63;
        int L  = t >> 9;
        int k  = ((ln >> 5) << 3) + j;
        w1pk[t] = (k < 4) ? (f16)W1[L * 128 + k * 32 + (ln & 31)] : (f16)0.f;
    }
    // zero slots + bar (grid-stride float4)
    float4 zv = {0.f, 0.f, 0.f, 0.f};
    float4* zp = reinterpret_cast<float4*>(zbase);
    const int total4 = ZERO_DWORDS >> 2;
    for (int t4 = i; t4 < total4; t4 += PKBLK * 256)
        zp[t4] = zv;
}

// ---------------------------------------------------------------------------
// Fused persistent kernel: all 8 layers; z, logdet in registers throughout.
// ---------------------------------------------------------------------------
__global__ void __launch_bounds__(TPB, 4)
flow_fused(const float* __restrict__ x,    const float* __restrict__ logdet,
           const float* __restrict__ bvec, const float* __restrict__ logs,
           const float* __restrict__ log_gamma,
           const float* __restrict__ b1,   const float* __restrict__ b2,
           const float* __restrict__ bf,
           const f16* __restrict__ w1pk,   const f16* __restrict__ w2pk,
           const f16* __restrict__ wfpk,
           float* __restrict__ out,        float* slots,
           unsigned* __restrict__ bar)
{
    const int tid  = threadIdx.x;
    const int bid  = blockIdx.x;
    const int lane = tid & 63;
    const int wid  = tid >> 6;          // 16 waves
    const bool lo  = lane < 32;
    const int slot = bid & (NSLOT - 1);
    // bit-reversed low-4 lane bits: component index after payload-halving butterfly
    const int br = ((lane & 1) << 3) | ((lane & 2) << 1) | ((lane & 4) >> 1) | ((lane & 8) >> 3);
    const size_t r0 = (size_t)bid * TPB + tid;

    __shared__ float lred[16 * 16];

    // ---- load row + logdet (persistent registers) ----
    float z[8];
    {
        const float4* p0 = reinterpret_cast<const float4*>(x + r0 * 8);
        float4 a = p0[0], c = p0[1];
        z[0]=a.x; z[1]=a.y; z[2]=a.z; z[3]=a.w;
        z[4]=c.x; z[5]=c.y; z[6]=c.z; z[7]=c.w;
    }
    float ldv = logdet[r0];

    // ---- initial partials of x -> slots[0] (payload-halving butterfly) ----
    {
        float acc[16];
        #pragma unroll
        for (int j = 0; j < 8; ++j) { acc[j] = z[j]; acc[8 + j] = z[j] * z[j]; }
        #pragma unroll
        for (int i = 0; i < 8; ++i) {
            float snd = (lane & 1) ? acc[i] : acc[8 + i];
            float kp  = (lane & 1) ? acc[8 + i] : acc[i];
            acc[i] = kp + __shfl_xor(snd, 1, 64);
        }
        #pragma unroll
        for (int i = 0; i < 4; ++i) {
            float snd = (lane & 2) ? acc[i] : acc[4 + i];
            float kp  = (lane & 2) ? acc[4 + i] : acc[i];
            acc[i] = kp + __shfl_xor(snd, 2, 64);
        }
        #pragma unroll
        for (int i = 0; i < 2; ++i) {
            float snd = (lane & 4) ? acc[i] : acc[2 + i];
            float kp  = (lane & 4) ? acc[2 + i] : acc[i];
            acc[i] = kp + __shfl_xor(snd, 4, 64);
        }
        {
            float snd = (lane & 8) ? acc[0] : acc[1];
            float kp  = (lane & 8) ? acc[1] : acc[0];
            acc[0] = kp + __shfl_xor(snd, 8, 64);
        }
        acc[0] += __shfl_xor(acc[0], 16, 64);
        acc[0] += __shfl_xor(acc[0], 32, 64);
        if (lane < 16) lred[wid * 16 + br] = acc[0];
        __syncthreads();
        if (tid < 16) {
            float s = 0.f;
            #pragma unroll
            for (int w = 0; w < 16; ++w) s += lred[w * 16 + tid];
            __hip_atomic_fetch_add(slots + (size_t)(tid * NSLOT + slot) * PADW, s,
                                   __ATOMIC_RELAXED, __HIP_MEMORY_SCOPE_AGENT);
        }
    }
    gbar(bar, 1);

    const f16x8* w1p = reinterpret_cast<const f16x8*>(w1pk);
    const f16x8* w2p = reinterpret_cast<const f16x8*>(w2pk);
    const f16x8* wfp = reinterpret_cast<const f16x8*>(wfpk);

    #pragma unroll 1
    for (int L = 0; L < 8; ++L) {
        // hoist A-fragment loads (latency hides under the stats stage)
        const f16x8 W1A = w1p[L * 64 + lane];
        const f16x8 A0  = w2p[(L * 2 + 0) * 64 + lane];
        const f16x8 A1  = w2p[(L * 2 + 1) * 64 + lane];
        const f16x8 F0  = wfp[(L * 2 + 0) * 64 + lane];
        const f16x8 F1  = wfp[(L * 2 + 1) * 64 + lane];

        // ---- stats: wave 0 reads padded slots, butterflies, computes DERIVED
        //      values (es/beta/gfac/sum_s) once, LDS-broadcasts 21 floats ----
        float es[8], beta[8], gfac[4], sum_s;
        {
            const float* sl = slots + (size_t)L * SLOT_DW;
            if (wid == 0) {
                float a16[16];
                #pragma unroll
                for (int j = 0; j < 16; ++j)
                    a16[j] = __hip_atomic_load(sl + (size_t)(j * NSLOT + lane) * PADW,
                                               __ATOMIC_RELAXED,
                                               __HIP_MEMORY_SCOPE_AGENT);
                #pragma unroll
                for (int d = 1; d < 64; d <<= 1) {
                    #pragma unroll
                    for (int j = 0; j < 16; ++j) a16[j] += __shfl_xor(a16[j], d, 64);
                }
                const float invB = 1.0f / (float)B_ROWS;
                float lv[21];
                float ss = 0.f;
                #pragma unroll
                for (int j = 0; j < 8; ++j) {
                    float m = a16[j] * invB;
                    float q = a16[8 + j] * invB;
                    float v = q - m * m;
                    v = v < 0.f ? 0.f : v;
                    float li = -(1.0f / 3.0f) * __logf(sqrtf(v) + 1e-6f);
                    float s = logs[L * 8 + j] + li;
                    s = s < -5.f ? -5.f : (s > 5.f ? 5.f : s);
                    lv[j]     = __expf(s);
                    lv[8 + j] = bvec[L * 8 + j] - m;
                    ss += s;
                }
                #pragma unroll
                for (int j = 0; j < 4; ++j) {
                    float lg = log_gamma[L * 4 + j];
                    lg = lg < -5.f ? -5.f : (lg > 5.f ? 5.f : lg);
                    lv[16 + j] = __expf(lg);
                }
                lv[20] = ss;
                if (lane == 0) {
                    #pragma unroll
                    for (int j = 0; j < 21; ++j) lred[j] = lv[j];
                }
            }
            __syncthreads();
            #pragma unroll
            for (int j = 0; j < 8; ++j) { es[j] = lred[j]; beta[j] = lred[8 + j]; }
            #pragma unroll
            for (int j = 0; j < 4; ++j) gfac[j] = lred[16 + j];
            sum_s = lred[20];
            __syncthreads();   // all reads done before lred reuse
        }

        // ---- actnorm ----
        #pragma unroll
        for (int j = 0; j < 8; ++j)
            z[j] = (z[j] + beta[j]) * es[j];

        const float* vb1 = b1 + L * 32;
        const float* vb2 = b2 + L * 32;
        const float* vbf = bf + L * 8;

        // ---- W1 via MFMA: h1^T = W1^T(padded K=16) @ z1^T ----
        float zp0 = pkh(z[0], z[1]);
        float zp1 = pkh(z[2], z[3]);
        u32x2 s0 = pls(zp0, 0.f);
        u32x2 s1 = pls(zp1, 0.f);
        f16x8 Z0 = mk8(bcf(s0[0]), bcf(s1[0]), 0.f, 0.f);   // rows 0-31
        f16x8 Z1 = mk8(bcf(s0[1]), bcf(s1[1]), 0.f, 0.f);   // rows 32-63

        f32x16 g0 = {}, g1 = {};
        g0 = __builtin_amdgcn_mfma_f32_32x32x16_f16(W1A, Z0, g0, 0, 0, 0);
        g1 = __builtin_amdgcn_mfma_f32_32x32x16_f16(W1A, Z1, g1, 0, 0, 0);

        // bias + relu + pack to f16 pairs
        float qg0[8], qg1[8];
        {
            float h0[16], h1v[16];
            #pragma unroll
            for (int r = 0; r < 16; ++r) {
                int wlo = (r & 3) + 8 * (r >> 2);
                float bsel = lo ? vb1[wlo] : vb1[wlo + 4];
                float a = g0[r] + bsel; h0[r]  = a > 0.f ? a : 0.f;
                float b = g1[r] + bsel; h1v[r] = b > 0.f ? b : 0.f;
            }
            #pragma unroll
            for (int c = 0; c < 8; ++c) {
                qg0[c] = pkh(h0[2 * c], h0[2 * c + 1]);
                qg1[c] = pkh(h1v[2 * c], h1v[2 * c + 1]);
            }
        }

        // ---- W2 B-frags via permlane32_swap ----
        u32x2 pA = pls(qg0[0], qg0[2]);
        u32x2 pB = pls(qg0[1], qg0[3]);
        u32x2 pC = pls(qg0[4], qg0[6]);
        u32x2 pD = pls(qg0[5], qg0[7]);
        f16x8 B00 = mk8(bcf(pA[0]), bcf(pB[0]), bcf(pA[1]), bcf(pB[1]));
        f16x8 B01 = mk8(bcf(pC[0]), bcf(pD[0]), bcf(pC[1]), bcf(pD[1]));
        pA = pls(qg1[0], qg1[2]);
        pB = pls(qg1[1], qg1[3]);
        pC = pls(qg1[4], qg1[6]);
        pD = pls(qg1[5], qg1[7]);
        f16x8 B10 = mk8(bcf(pA[0]), bcf(pB[0]), bcf(pA[1]), bcf(pB[1]));
        f16x8 B11 = mk8(bcf(pC[0]), bcf(pD[0]), bcf(pC[1]), bcf(pD[1]));

        f32x16 d0 = {}, d1 = {};
        d0 = __builtin_amdgcn_mfma_f32_32x32x16_f16(A0, B00, d0, 0, 0, 0);
        d0 = __builtin_amdgcn_mfma_f32_32x32x16_f16(A1, B01, d0, 0, 0, 0);
        d1 = __builtin_amdgcn_mfma_f32_32x32x16_f16(A0, B10, d1, 0, 0, 0);
        d1 = __builtin_amdgcn_mfma_f32_32x32x16_f16(A1, B11, d1, 0, 0, 0);

        // ---- + b2, relu, pack ----
        float P0[8], P1[8];
        {
            float h2g0[16], h2g1[16];
            #pragma unroll
            for (int r = 0; r < 16; ++r) {
                int wlo = (r & 3) + 8 * (r >> 2);
                float bsel = lo ? vb2[wlo] : vb2[wlo + 4];
                float a = d0[r] + bsel; h2g0[r] = a > 0.f ? a : 0.f;
                float b = d1[r] + bsel; h2g1[r] = b > 0.f ? b : 0.f;
            }
            #pragma unroll
            for (int c = 0; c < 8; ++c) {
                P0[c] = pkh(h2g0[2 * c], h2g0[2 * c + 1]);
                P1[c] = pkh(h2g1[2 * c], h2g1[2 * c + 1]);
            }
        }

        // ---- Wf C-frags via permlane32_swap ----
        u32x2 pE = pls(P0[0], P0[2]);
        u32x2 pF = pls(P0[1], P0[3]);
        u32x2 pG = pls(P0[4], P0[6]);
        u32x2 pH = pls(P0[5], P0[7]);
        f16x8 C00 = mk8(bcf(pE[0]), bcf(pF[0]), bcf(pE[1]), bcf(pF[1]));
        f16x8 C01 = mk8(bcf(pG[0]), bcf(pH[0]), bcf(pG[1]), bcf(pH[1]));
        pE = pls(P1[0], P1[2]);
        pF = pls(P1[1], P1[3]);
        pG = pls(P1[4], P1[6]);
        pH = pls(P1[5], P1[7]);
        f16x8 C10 = mk8(bcf(pE[0]), bcf(pF[0]), bcf(pE[1]), bcf(pF[1]));
        f16x8 C11 = mk8(bcf(pG[0]), bcf(pH[0]), bcf(pG[1]), bcf(pH[1]));

        f32x16 e0 = {}, e1 = {};
        e0 = __builtin_amdgcn_mfma_f32_32x32x16_f16(F0, C00, e0, 0, 0, 0);
        e0 = __builtin_amdgcn_mfma_f32_32x32x16_f16(F1, C01, e0, 0, 0, 0);
        e1 = __builtin_amdgcn_mfma_f32_32x32x16_f16(F0, C10, e1, 0, 0, 0);
        e1 = __builtin_amdgcn_mfma_f32_32x32x16_f16(F1, C11, e1, 0, 0, 0);

        // ---- gather own row's h3 via permlane32_swap ----
        float h3[8];
        #pragma unroll
        for (int r = 0; r < 4; ++r) {
            u32x2 pe = pls(e0[r], e1[r]);
            h3[r]     = bcf(pe[0]) + vbf[r];
            h3[r + 4] = bcf(pe[1]) + vbf[r + 4];
        }

        // ---- coupling epilogue + permutation + next-layer partials ----
        float nacc[16];
        {
            float ldl = 0.f;
            float nz[8];
            #pragma unroll
            for (int j = 0; j < 4; ++j) {
                float sc = 0.6f * fast_tanh(h3[2 * j + 1]);
                float sh = gfac[j] * fast_tanh(h3[2 * j]);
                float z2 = z[4 + j];
                z2 = z2 + sc * z2 + sh;
                ldl += __logf(1.0f + sc);
                nz[3 - j] = z2;      // reversed: out[3-j] = z2_j
                nz[7 - j] = z[j];    // reversed: out[7-j] = z1_j
            }
            ldv += sum_s + ldl;
            #pragma unroll
            for (int j = 0; j < 8; ++j) {
                z[j] = nz[j];
                nacc[j]     = nz[j];
                nacc[8 + j] = nz[j] * nz[j];
            }
        }

        if (L < 7) {
            #pragma unroll
            for (int i = 0; i < 8; ++i) {
                float snd = (lane & 1) ? nacc[i] : nacc[8 + i];
                float kp  = (lane & 1) ? nacc[8 + i] : nacc[i];
                nacc[i] = kp + __shfl_xor(snd, 1, 64);
            }
            #pragma unroll
            for (int i = 0; i < 4; ++i) {
                float snd = (lane & 2) ? nacc[i] : nacc[4 + i];
                float kp  = (lane & 2) ? nacc[4 + i] : nacc[i];
                nacc[i] = kp + __shfl_xor(snd, 2, 64);
            }
            #pragma unroll
            for (int i = 0; i < 2; ++i) {
                float snd = (lane & 4) ? nacc[i] : nacc[2 + i];
                float kp  = (lane & 4) ? nacc[2 + i] : nacc[i];
                nacc[i] = kp + __shfl_xor(snd, 4, 64);
            }
            {
                float snd = (lane & 8) ? nacc[0] : nacc[1];
                float kp  = (lane & 8) ? nacc[1] : nacc[0];
                nacc[0] = kp + __shfl_xor(snd, 8, 64);
            }
            nacc[0] += __shfl_xor(nacc[0], 16, 64);
            nacc[0] += __shfl_xor(nacc[0], 32, 64);
            if (lane < 16) lred[wid * 16 + br] = nacc[0];
            __syncthreads();
            if (tid < 16) {
                float s = 0.f;
                #pragma unroll
                for (int w = 0; w < 16; ++w) s += lred[w * 16 + tid];
                __hip_atomic_fetch_add(slots + (size_t)(L + 1) * SLOT_DW +
                                           (size_t)(tid * NSLOT + slot) * PADW, s,
                                       __ATOMIC_RELAXED, __HIP_MEMORY_SCOPE_AGENT);
            }
            gbar(bar, (unsigned)(L + 2));
        }
    }

    // ---- store outputs: z (B,8) then ld (B,1) ----
    {
        float4* p0 = reinterpret_cast<float4*>(out + r0 * 8);
        float4 a, c;
        a.x=z[0]; a.y=z[1]; a.z=z[2]; a.w=z[3];
        c.x=z[4]; c.y=z[5]; c.z=z[6]; c.w=z[7];
        p0[0] = a; p0[1] = c;
    }
    out[(size_t)B_ROWS * 8 + r0] = ldv;
}

extern "C" void kernel_launch(void* const* d_in, const int* in_sizes, int n_in,
                              void* d_out, int out_size, void* d_ws, size_t ws_size,
                              hipStream_t stream) {
    const float* x      = (const float*)d_in[0];
    const float* logdet = (const float*)d_in[1];
    const float* bvec   = (const float*)d_in[2];
    const float* logs   = (const float*)d_in[3];
    const float* lg     = (const float*)d_in[4];
    const float* W1     = (const float*)d_in[5];
    const float* b1     = (const float*)d_in[6];
    const float* W2     = (const float*)d_in[7];
    const float* b2     = (const float*)d_in[8];
    const float* Wf     = (const float*)d_in[9];
    const float* bf     = (const float*)d_in[10];
    float* out = (float*)d_out;

    // ws layout: w1pk[8192 B] | w2pk[16384 B] | wfpk[16384 B]
    //            | slots[SLOTS_TOTAL_DW f32] | bar[BAR_DWORDS u32]
    f16*      w1pk  = (f16*)d_ws;
    f16*      w2pk  = w1pk + 4096;
    f16*      wfpk  = w2pk + 8192;
    float*    slots = (float*)(wfpk + 8192);
    unsigned* bar   = (unsigned*)(slots + SLOTS_TOTAL_DW);

    pack_weights<<<PKBLK, 256, 0, stream>>>(W1, W2, Wf, w1pk, w2pk, wfpk, slots);

    void* args[] = {&x, &logdet, &bvec, &logs, &lg, &b1, &b2, &bf,
                    &w1pk, &w2pk, &wfpk, &out, &slots, &bar};
    hipLaunchKernel(reinterpret_cast<void*>(&flow_fused),
                    dim3(NBLK), dim3(TPB), args, 0, stream);
}